// Round 6
// baseline (252.627 us; speedup 1.0000x reference)
//
#include <hip/hip_runtime.h>

typedef unsigned short u16;
typedef unsigned int   u32;

#define NB     20000   // batch of target nodes
#define SNB    25      // sampled neighbors (padded)
#define FEAT   256
#define K2     512     // 2*FEAT
#define OUTF   256
#define NNODES 100000

// Round-6: linearity trick. out[b] = relu(P[nodes[b]] + mean_s Q[neighs[b,s]])
// with T = [P|Q] = feats @ Wt^T precomputed bf16 [100000][512].
//   Wt[j][k] = (j<256) ? w1[j][k] : w1[j-256][256+k]
// Gather now pulls 512B bf16 half-rows (cols 0:256 for self, 256:512 for
// neighbors) instead of 1KB f32 rows: logical gather 280 -> 143 MB. The old
// combined round-trip and consumer GEMM vanish; the table GEMM streams feats
// from HBM once (compulsory read anyway).
// Evidence: R5 isolated agg = 61.8us at 4.5 TB/s logical, ~10x latency slack
// -> service-rate ceiling on random row pulls; halving bytes is the lever.
//
// d_ws layout: T bf16 [100000][512] at 0 (102,400,000 B);
//              Wt bf16 [512][256]  at WS_WT_OFF (262,144 B).
// Fallback (ws too small): proven round-0 split path.
#define WS_T_BYTES   (NNODES * K2 * 2)
#define WS_WT_OFF    WS_T_BYTES
#define WS_WT_BYTES  (K2 * FEAT * 2)
#define WS_NEED      (WS_WT_OFF + WS_WT_BYTES)

#define WSF_W1_OFF   (NB * K2 * 2)
#define WSF_NEED     (WSF_W1_OFF + WS_WT_BYTES)

typedef __attribute__((ext_vector_type(8))) short short8;
typedef __attribute__((ext_vector_type(4))) float f32x4;

__device__ __forceinline__ u32 f2bf(float f) {
  union { u32 i; float f; } x; x.f = f;
  return (x.i + 0x7fffu + ((x.i >> 16) & 1u)) >> 16;  // RNE
}
__device__ __forceinline__ u32 pack2(float a, float b) {
  return f2bf(a) | (f2bf(b) << 16);
}
__device__ __forceinline__ float4 unbf4(uint2 u) {
  float4 r;
  r.x = __uint_as_float(u.x << 16);
  r.y = __uint_as_float(u.x & 0xffff0000u);
  r.z = __uint_as_float(u.y << 16);
  r.w = __uint_as_float(u.y & 0xffff0000u);
  return r;
}

// ---------------------------------------------------------------------------
// Build Wt bf16 [512][256]: row j<256 = w1[j][0:256]; row j>=256 = w1[j-256][256:512].
// ---------------------------------------------------------------------------
__global__ __launch_bounds__(256) void convwt_kernel(
    const float* __restrict__ w1, u16* __restrict__ wt) {
  const int idx = blockIdx.x * 256 + threadIdx.x;   // 512 blocks -> 131072
  const int j = idx >> 8;
  const int k = idx & 255;
  const float v = (j < 256) ? w1[j * K2 + k] : w1[(j - 256) * K2 + 256 + k];
  wt[idx] = (u16)f2bf(v);
}

// ---------------------------------------------------------------------------
// Table GEMM: T[100000,512] = feats[100000,256](->bf16) @ Wt[512,256]^T, bf16 out.
// Round-0-proven structure: 128x128 tile, BK=32, 4 waves 2x2, wave 64x64 =
// 4x4 MFMA 16x16x32 bf16, LDS stage with +8 row pad. f32->bf16 pack folded
// into A staging. Grid 782x4 = 3128 blocks -> ~12 blocks/CU queued.
// NO relu here: T holds pre-activation linear parts.
// ---------------------------------------------------------------------------
#define TM   128
#define TBK  32
#define LDST 40   // 32 + 8 pad elems

__global__ __launch_bounds__(256) void tgemm_kernel(
    const float* __restrict__ feats,  // [100000, 256] f32
    const u16* __restrict__ Wt,       // [512, 256] bf16 (K-contiguous)
    u16* __restrict__ T) {            // [100000, 512] bf16
  __shared__ u16 As[TM * LDST];
  __shared__ u16 Bs[TM * LDST];

  const int tid  = threadIdx.x;
  const int wave = tid >> 6;
  const int lane = tid & 63;
  const int m0 = blockIdx.x * TM;
  const int n0 = blockIdx.y * TM;

  const int wr = (wave >> 1) * 64;
  const int wc = (wave & 1) * 64;

  f32x4 acc[4][4] = {};

  const int r16 = lane & 15;
  const int kq  = (lane >> 4) * 8;

  const int sr = tid >> 1;   // staging row 0..127
  const int sh = tid & 1;    // 16-elem half of the 32-elem k-slice

  for (int k0 = 0; k0 < FEAT; k0 += TBK) {
    // A: 128 rows x 32 f32 -> bf16. Thread: 4 float4 loads, 2 uint4 stores.
    {
      int ar = m0 + sr; if (ar >= NNODES) ar = NNODES - 1;
      const float4* src = (const float4*)(feats + (size_t)ar * FEAT + k0 + sh * 16);
      const float4 f0 = src[0], f1 = src[1], f2 = src[2], f3 = src[3];
      uint4 o0, o1;
      o0.x = pack2(f0.x, f0.y); o0.y = pack2(f0.z, f0.w);
      o0.z = pack2(f1.x, f1.y); o0.w = pack2(f1.z, f1.w);
      o1.x = pack2(f2.x, f2.y); o1.y = pack2(f2.z, f2.w);
      o1.z = pack2(f3.x, f3.y); o1.w = pack2(f3.z, f3.w);
      *(uint4*)&As[sr * LDST + sh * 16]     = o0;
      *(uint4*)&As[sr * LDST + sh * 16 + 8] = o1;
    }
    // B: 128 rows x 32 bf16 of Wt. Thread: 2 uint4 loads, 2 uint4 stores.
    {
      const uint4* src = (const uint4*)(Wt + (size_t)(n0 + sr) * FEAT + k0 + sh * 16);
      *(uint4*)&Bs[sr * LDST + sh * 16]     = src[0];
      *(uint4*)&Bs[sr * LDST + sh * 16 + 8] = src[1];
    }
    __syncthreads();

    short8 af[4], bf[4];
#pragma unroll
    for (int i = 0; i < 4; ++i)
      af[i] = *(const short8*)&As[(wr + i * 16 + r16) * LDST + kq];
#pragma unroll
    for (int j = 0; j < 4; ++j)
      bf[j] = *(const short8*)&Bs[(wc + j * 16 + r16) * LDST + kq];

#pragma unroll
    for (int i = 0; i < 4; ++i)
#pragma unroll
      for (int j = 0; j < 4; ++j)
        acc[i][j] = __builtin_amdgcn_mfma_f32_16x16x32_bf16(af[i], bf[j],
                                                            acc[i][j], 0, 0, 0);
    __syncthreads();
  }

  // Epilogue: C/D layout col = lane&15, row = (lane>>4)*4 + reg [m89]; bf16 out.
#pragma unroll
  for (int i = 0; i < 4; ++i) {
#pragma unroll
    for (int r = 0; r < 4; ++r) {
      const int row = m0 + wr + i * 16 + (lane >> 4) * 4 + r;
      if (row < NNODES) {
#pragma unroll
        for (int j = 0; j < 4; ++j) {
          const int col = n0 + wc + j * 16 + r16;
          T[(size_t)row * K2 + col] = (u16)f2bf(acc[i][j][r]);
        }
      }
    }
  }
}

// ---------------------------------------------------------------------------
// Final gather: out[b] = relu(P[nodes[b]] + mean_s Q[neighs[b,s]]).
// Wave per node (proven agg structure), 8 gathers in flight; rows are now
// 512B bf16 half-rows (lane covers 4 feats via uint2 = 8B).
// ---------------------------------------------------------------------------
__global__ __launch_bounds__(256) void final_kernel(
    const u16* __restrict__ T, const int* __restrict__ nodes,
    const int* __restrict__ neighs, const int* __restrict__ lens,
    float* __restrict__ C) {
  const int b    = blockIdx.x * 4 + (threadIdx.x >> 6);
  const int lane = threadIdx.x & 63;

  const int self = nodes[b];
  const int len  = lens[b];   // >= 1
  int myidx = (lane < SNB) ? neighs[b * SNB + lane] : 0;

  // self: P half (cols 0:256)
  const uint2 sp = *(const uint2*)(T + (size_t)self * K2 + lane * 4);
  const float4 p = unbf4(sp);

  // neighbors: Q half (cols 256:512)
  float4 a0 = {0.f, 0.f, 0.f, 0.f}, a1 = a0, a2 = a0, a3 = a0;
  float4 a4 = a0, a5 = a0, a6 = a0, a7 = a0;
  int s = 0;
  for (; s + 8 <= len; s += 8) {
    const int i0 = __shfl(myidx, s);
    const int i1 = __shfl(myidx, s + 1);
    const int i2 = __shfl(myidx, s + 2);
    const int i3 = __shfl(myidx, s + 3);
    const int i4 = __shfl(myidx, s + 4);
    const int i5 = __shfl(myidx, s + 5);
    const int i6 = __shfl(myidx, s + 6);
    const int i7 = __shfl(myidx, s + 7);
    const uint2 q0 = *(const uint2*)(T + (size_t)i0 * K2 + 256 + lane * 4);
    const uint2 q1 = *(const uint2*)(T + (size_t)i1 * K2 + 256 + lane * 4);
    const uint2 q2 = *(const uint2*)(T + (size_t)i2 * K2 + 256 + lane * 4);
    const uint2 q3 = *(const uint2*)(T + (size_t)i3 * K2 + 256 + lane * 4);
    const uint2 q4 = *(const uint2*)(T + (size_t)i4 * K2 + 256 + lane * 4);
    const uint2 q5 = *(const uint2*)(T + (size_t)i5 * K2 + 256 + lane * 4);
    const uint2 q6 = *(const uint2*)(T + (size_t)i6 * K2 + 256 + lane * 4);
    const uint2 q7 = *(const uint2*)(T + (size_t)i7 * K2 + 256 + lane * 4);
    float4 v;
    v = unbf4(q0); a0.x += v.x; a0.y += v.y; a0.z += v.z; a0.w += v.w;
    v = unbf4(q1); a1.x += v.x; a1.y += v.y; a1.z += v.z; a1.w += v.w;
    v = unbf4(q2); a2.x += v.x; a2.y += v.y; a2.z += v.z; a2.w += v.w;
    v = unbf4(q3); a3.x += v.x; a3.y += v.y; a3.z += v.z; a3.w += v.w;
    v = unbf4(q4); a4.x += v.x; a4.y += v.y; a4.z += v.z; a4.w += v.w;
    v = unbf4(q5); a5.x += v.x; a5.y += v.y; a5.z += v.z; a5.w += v.w;
    v = unbf4(q6); a6.x += v.x; a6.y += v.y; a6.z += v.z; a6.w += v.w;
    v = unbf4(q7); a7.x += v.x; a7.y += v.y; a7.z += v.z; a7.w += v.w;
  }
  for (; s < len; ++s) {
    const int i0 = __shfl(myidx, s);
    const uint2 q0 = *(const uint2*)(T + (size_t)i0 * K2 + 256 + lane * 4);
    const float4 v = unbf4(q0);
    a0.x += v.x; a0.y += v.y; a0.z += v.z; a0.w += v.w;
  }
  a0.x += a4.x; a0.y += a4.y; a0.z += a4.z; a0.w += a4.w;
  a1.x += a5.x; a1.y += a5.y; a1.z += a5.z; a1.w += a5.w;
  a2.x += a6.x; a2.y += a6.y; a2.z += a6.z; a2.w += a6.w;
  a3.x += a7.x; a3.y += a7.y; a3.z += a7.z; a3.w += a7.w;
  const float inv = 1.f / (float)len;
  float4 o;
  o.x = p.x + (a0.x + a1.x + a2.x + a3.x) * inv;
  o.y = p.y + (a0.y + a1.y + a2.y + a3.y) * inv;
  o.z = p.z + (a0.z + a1.z + a2.z + a3.z) * inv;
  o.w = p.w + (a0.w + a1.w + a2.w + a3.w) * inv;
  o.x = o.x > 0.f ? o.x : 0.f;
  o.y = o.y > 0.f ? o.y : 0.f;
  o.z = o.z > 0.f ? o.z : 0.f;
  o.w = o.w > 0.f ? o.w : 0.f;
  ((float4*)(C + (size_t)b * OUTF))[lane] = o;
}

// ===========================================================================
// FALLBACK path (ws too small): proven round-0/5 split kernels.
// ===========================================================================
__global__ __launch_bounds__(256) void convw_fb_kernel(
    const float* __restrict__ w_raw, u16* __restrict__ w_bf) {
  const int i = blockIdx.x * 256 + threadIdx.x;
  w_bf[i] = (u16)f2bf(w_raw[i]);
}

__global__ __launch_bounds__(256) void agg_fb_kernel(
    const float* __restrict__ feats, const int* __restrict__ nodes,
    const int* __restrict__ neighs, const int* __restrict__ lens,
    u16* __restrict__ combined) {
  const int b    = blockIdx.x * 4 + (threadIdx.x >> 6);
  const int lane = threadIdx.x & 63;
  const int self = nodes[b];
  const int len  = lens[b];
  int myidx = (lane < SNB) ? neighs[b * SNB + lane] : 0;
  const float4 sv = ((const float4*)(feats + (size_t)self * FEAT))[lane];
  float4 a0 = {0.f, 0.f, 0.f, 0.f}, a1 = a0, a2 = a0, a3 = a0;
  int s = 0;
  for (; s + 4 <= len; s += 4) {
    const int i0 = __shfl(myidx, s);
    const int i1 = __shfl(myidx, s + 1);
    const int i2 = __shfl(myidx, s + 2);
    const int i3 = __shfl(myidx, s + 3);
    const float4 v0 = ((const float4*)(feats + (size_t)i0 * FEAT))[lane];
    const float4 v1 = ((const float4*)(feats + (size_t)i1 * FEAT))[lane];
    const float4 v2 = ((const float4*)(feats + (size_t)i2 * FEAT))[lane];
    const float4 v3 = ((const float4*)(feats + (size_t)i3 * FEAT))[lane];
    a0.x += v0.x; a0.y += v0.y; a0.z += v0.z; a0.w += v0.w;
    a1.x += v1.x; a1.y += v1.y; a1.z += v1.z; a1.w += v1.w;
    a2.x += v2.x; a2.y += v2.y; a2.z += v2.z; a2.w += v2.w;
    a3.x += v3.x; a3.y += v3.y; a3.z += v3.z; a3.w += v3.w;
  }
  for (; s < len; ++s) {
    const int i0 = __shfl(myidx, s);
    const float4 v0 = ((const float4*)(feats + (size_t)i0 * FEAT))[lane];
    a0.x += v0.x; a0.y += v0.y; a0.z += v0.z; a0.w += v0.w;
  }
  const float inv = 1.f / (float)len;
  const float m0 = (a0.x + a1.x + a2.x + a3.x) * inv;
  const float m1 = (a0.y + a1.y + a2.y + a3.y) * inv;
  const float m2 = (a0.z + a1.z + a2.z + a3.z) * inv;
  const float m3 = (a0.w + a1.w + a2.w + a3.w) * inv;
  uint2* crow = (uint2*)(combined + (size_t)b * K2);
  uint2 pe; pe.x = pack2(sv.x, sv.y); pe.y = pack2(sv.z, sv.w);
  crow[lane] = pe;
  uint2 pm; pm.x = pack2(m0, m1); pm.y = pack2(m2, m3);
  crow[64 + lane] = pm;
}

__global__ __launch_bounds__(256) void gemm_fb_kernel(
    const u16* __restrict__ A, const u16* __restrict__ W,
    float* __restrict__ C, int M) {
  __shared__ u16 As[128 * LDST];
  __shared__ u16 Bs[128 * LDST];
  const int tid  = threadIdx.x;
  const int wave = tid >> 6;
  const int lane = tid & 63;
  const int m0 = blockIdx.x * 128;
  const int n0 = blockIdx.y * 128;
  const int wr = (wave >> 1) * 64;
  const int wc = (wave & 1) * 64;
  f32x4 acc[4][4] = {};
  const int r16 = lane & 15;
  const int kq  = (lane >> 4) * 8;
  const int srow = tid >> 2;
  const int skc  = tid & 3;
  for (int k0 = 0; k0 < K2; k0 += 32) {
#pragma unroll
    for (int i = 0; i < 2; ++i) {
      const int row = i * 64 + srow;
      int ar = m0 + row; if (ar >= M) ar = M - 1;
      const uint4 va = ((const uint4*)(A + (size_t)ar * K2 + k0))[skc];
      *(uint4*)&As[row * LDST + skc * 8] = va;
      const uint4 vb = ((const uint4*)(W + (size_t)(n0 + row) * K2 + k0))[skc];
      *(uint4*)&Bs[row * LDST + skc * 8] = vb;
    }
    __syncthreads();
    short8 af[4], bf[4];
#pragma unroll
    for (int i = 0; i < 4; ++i)
      af[i] = *(const short8*)&As[(wr + i * 16 + r16) * LDST + kq];
#pragma unroll
    for (int j = 0; j < 4; ++j)
      bf[j] = *(const short8*)&Bs[(wc + j * 16 + r16) * LDST + kq];
#pragma unroll
    for (int i = 0; i < 4; ++i)
#pragma unroll
      for (int j = 0; j < 4; ++j)
        acc[i][j] = __builtin_amdgcn_mfma_f32_16x16x32_bf16(af[i], bf[j],
                                                            acc[i][j], 0, 0, 0);
    __syncthreads();
  }
#pragma unroll
  for (int i = 0; i < 4; ++i) {
#pragma unroll
    for (int r = 0; r < 4; ++r) {
      const int row = m0 + wr + i * 16 + (lane >> 4) * 4 + r;
      if (row < M) {
#pragma unroll
        for (int j = 0; j < 4; ++j) {
          const int col = n0 + wc + j * 16 + (lane & 15);
          float v = acc[i][j][r];
          C[(size_t)row * OUTF + col] = v > 0.f ? v : 0.f;
        }
      }
    }
  }
}

// ---------------------------------------------------------------------------
extern "C" void kernel_launch(void* const* d_in, const int* in_sizes, int n_in,
                              void* d_out, int out_size, void* d_ws, size_t ws_size,
                              hipStream_t stream) {
  const float* feats = (const float*)d_in[0];  // [100000, 256] f32
  const int* nodes   = (const int*)d_in[1];    // [20000]
  const int* neighs  = (const int*)d_in[2];    // [20000, 25]
  const int* lens    = (const int*)d_in[3];    // [20000]
  // d_in[4] = w0 — dead: layer-0 output is discarded by the reference loop.
  const float* w1    = (const float*)d_in[5];  // [256, 512] f32
  float* out = (float*)d_out;                  // [20000, 256] f32

  char* ws = (char*)d_ws;

  if (ws_size >= (size_t)WS_NEED) {
    u16* T  = (u16*)ws;                        // [100000, 512] bf16
    u16* Wt = (u16*)(ws + WS_WT_OFF);          // [512, 256] bf16

    convwt_kernel<<<512, 256, 0, stream>>>(w1, Wt);
    dim3 tg((NNODES + TM - 1) / TM, K2 / TM);  // 782 x 4
    tgemm_kernel<<<tg, 256, 0, stream>>>(feats, Wt, T);
    final_kernel<<<NB / 4, 256, 0, stream>>>(T, nodes, neighs, lens, out);
  } else {
    u16* combined = (u16*)ws;                  // [20000, 512] bf16
    u16* w1bf     = (u16*)(ws + WSF_W1_OFF);   // [256, 512] bf16
    convw_fb_kernel<<<512, 256, 0, stream>>>(w1, w1bf);
    agg_fb_kernel<<<NB / 4, 256, 0, stream>>>(feats, nodes, neighs, lens, combined);
    dim3 grid((NB + 127) / 128, OUTF / 128);
    gemm_fb_kernel<<<grid, 256, 0, stream>>>(combined, w1bf, out, NB);
  }
}

// Round 7
// 208.044 us; speedup vs baseline: 1.2143x; 1.2143x over previous
//
#include <hip/hip_runtime.h>

typedef unsigned short u16;
typedef unsigned int   u32;

#define NB     20000   // batch of target nodes
#define SNB    25      // sampled neighbors (padded)
#define FEAT   256
#define K2     512     // 2*FEAT
#define OUTF   256
#define NNODES 100000

// Round-7: cast-then-gather. Evidence chain:
//   R5: f32 agg isolated = 61.8us (280 MB logical gather of 1KB rows).
//   R6: bf16-row gather (final_kernel) = ~20us at same row count (512B rows)
//       -> gather cost ~ bytes/row. But tgemm (table build) cost 108us.
// So: build NO table. Cast feats f32->bf16 once (150 MB stream, ~25us),
// gather bf16 rows with the proven wave-per-node agg (~20us), then the
// proven round-0 128x128 LDS GEMM (~15us). Self half of combined is a
// bit-exact copy of the cast row (same values as old f2bf(f32) path).
//
// d_ws layout (bytes):
//   [0]           featsbf bf16 [100000][256] = 51,200,000
//   [51,200,000]  combined bf16 [20000][512] = 20,480,000
//   [71,680,000]  w1bf bf16 [256][512]       =    262,144
// (R6 ran its 102.7 MB layout -> ws_size >= 103 MB > 72 MB needed.)
#define WS_FB_OFF   0
#define WS_CMB_OFF  (NNODES * FEAT * 2)
#define WS_W1_OFF   (WS_CMB_OFF + NB * K2 * 2)

typedef __attribute__((ext_vector_type(8))) short short8;
typedef __attribute__((ext_vector_type(4))) float f32x4;

__device__ __forceinline__ u32 f2bf(float f) {
  union { u32 i; float f; } x; x.f = f;
  return (x.i + 0x7fffu + ((x.i >> 16) & 1u)) >> 16;  // RNE
}
__device__ __forceinline__ u32 pack2(float a, float b) {
  return f2bf(a) | (f2bf(b) << 16);
}
__device__ __forceinline__ float4 unbf4(uint2 u) {
  float4 r;
  r.x = __uint_as_float(u.x << 16);
  r.y = __uint_as_float(u.x & 0xffff0000u);
  r.z = __uint_as_float(u.y << 16);
  r.w = __uint_as_float(u.y & 0xffff0000u);
  return r;
}

// ---------------------------------------------------------------------------
// feats f32 -> bf16 (25.6M elems). 8 elems/thread: 2 float4 loads, 1 uint4
// store. 12500 blocks. Pure streaming, ~150 MB total traffic.
// ---------------------------------------------------------------------------
__global__ __launch_bounds__(256) void cast_kernel(
    const float* __restrict__ in, u16* __restrict__ out) {
  const int i = blockIdx.x * 256 + threadIdx.x;   // 8-elem group id
  const float4 f0 = ((const float4*)in)[(size_t)i * 2];
  const float4 f1 = ((const float4*)in)[(size_t)i * 2 + 1];
  uint4 o;
  o.x = pack2(f0.x, f0.y); o.y = pack2(f0.z, f0.w);
  o.z = pack2(f1.x, f1.y); o.w = pack2(f1.z, f1.w);
  ((uint4*)out)[i] = o;
}

// ---------------------------------------------------------------------------
// w1 f32 -> bf16 (131072 elements).
// ---------------------------------------------------------------------------
__global__ __launch_bounds__(256) void convw_kernel(
    const float* __restrict__ w_raw, u16* __restrict__ w_bf) {
  const int i = blockIdx.x * 256 + threadIdx.x;
  w_bf[i] = (u16)f2bf(w_raw[i]);
}

// ---------------------------------------------------------------------------
// Aggregation over bf16 rows: combined[b,0:256] = featsbf[nodes[b]] (copy);
// combined[b,256:512] = bf16(mean_f32(featsbf[neighs[b,:len]])).
// Proven wave-per-node structure (R0/R5), 8 gathers in flight; rows are now
// 512 B (lane covers 4 feats via uint2 = 8 B). No barriers.
// ---------------------------------------------------------------------------
__global__ __launch_bounds__(256) void agg_kernel(
    const u16* __restrict__ fb, const int* __restrict__ nodes,
    const int* __restrict__ neighs, const int* __restrict__ lens,
    u16* __restrict__ combined) {
  const int b    = blockIdx.x * 4 + (threadIdx.x >> 6);  // node id
  const int lane = threadIdx.x & 63;

  const int self = nodes[b];
  const int len  = lens[b];   // guaranteed >= 1
  int myidx = (lane < SNB) ? neighs[b * SNB + lane] : 0;

  const uint2 sp = *(const uint2*)(fb + (size_t)self * FEAT + lane * 4);

  float4 a0 = {0.f, 0.f, 0.f, 0.f}, a1 = a0, a2 = a0, a3 = a0;
  float4 a4 = a0, a5 = a0, a6 = a0, a7 = a0;
  int s = 0;
  for (; s + 8 <= len; s += 8) {
    const int i0 = __shfl(myidx, s);
    const int i1 = __shfl(myidx, s + 1);
    const int i2 = __shfl(myidx, s + 2);
    const int i3 = __shfl(myidx, s + 3);
    const int i4 = __shfl(myidx, s + 4);
    const int i5 = __shfl(myidx, s + 5);
    const int i6 = __shfl(myidx, s + 6);
    const int i7 = __shfl(myidx, s + 7);
    const uint2 q0 = *(const uint2*)(fb + (size_t)i0 * FEAT + lane * 4);
    const uint2 q1 = *(const uint2*)(fb + (size_t)i1 * FEAT + lane * 4);
    const uint2 q2 = *(const uint2*)(fb + (size_t)i2 * FEAT + lane * 4);
    const uint2 q3 = *(const uint2*)(fb + (size_t)i3 * FEAT + lane * 4);
    const uint2 q4 = *(const uint2*)(fb + (size_t)i4 * FEAT + lane * 4);
    const uint2 q5 = *(const uint2*)(fb + (size_t)i5 * FEAT + lane * 4);
    const uint2 q6 = *(const uint2*)(fb + (size_t)i6 * FEAT + lane * 4);
    const uint2 q7 = *(const uint2*)(fb + (size_t)i7 * FEAT + lane * 4);
    float4 v;
    v = unbf4(q0); a0.x += v.x; a0.y += v.y; a0.z += v.z; a0.w += v.w;
    v = unbf4(q1); a1.x += v.x; a1.y += v.y; a1.z += v.z; a1.w += v.w;
    v = unbf4(q2); a2.x += v.x; a2.y += v.y; a2.z += v.z; a2.w += v.w;
    v = unbf4(q3); a3.x += v.x; a3.y += v.y; a3.z += v.z; a3.w += v.w;
    v = unbf4(q4); a4.x += v.x; a4.y += v.y; a4.z += v.z; a4.w += v.w;
    v = unbf4(q5); a5.x += v.x; a5.y += v.y; a5.z += v.z; a5.w += v.w;
    v = unbf4(q6); a6.x += v.x; a6.y += v.y; a6.z += v.z; a6.w += v.w;
    v = unbf4(q7); a7.x += v.x; a7.y += v.y; a7.z += v.z; a7.w += v.w;
  }
  for (; s + 4 <= len; s += 4) {
    const int i0 = __shfl(myidx, s);
    const int i1 = __shfl(myidx, s + 1);
    const int i2 = __shfl(myidx, s + 2);
    const int i3 = __shfl(myidx, s + 3);
    const uint2 q0 = *(const uint2*)(fb + (size_t)i0 * FEAT + lane * 4);
    const uint2 q1 = *(const uint2*)(fb + (size_t)i1 * FEAT + lane * 4);
    const uint2 q2 = *(const uint2*)(fb + (size_t)i2 * FEAT + lane * 4);
    const uint2 q3 = *(const uint2*)(fb + (size_t)i3 * FEAT + lane * 4);
    float4 v;
    v = unbf4(q0); a0.x += v.x; a0.y += v.y; a0.z += v.z; a0.w += v.w;
    v = unbf4(q1); a1.x += v.x; a1.y += v.y; a1.z += v.z; a1.w += v.w;
    v = unbf4(q2); a2.x += v.x; a2.y += v.y; a2.z += v.z; a2.w += v.w;
    v = unbf4(q3); a3.x += v.x; a3.y += v.y; a3.z += v.z; a3.w += v.w;
  }
  for (; s < len; ++s) {
    const int i0 = __shfl(myidx, s);
    const uint2 q0 = *(const uint2*)(fb + (size_t)i0 * FEAT + lane * 4);
    const float4 v = unbf4(q0);
    a0.x += v.x; a0.y += v.y; a0.z += v.z; a0.w += v.w;
  }
  a0.x += a4.x; a0.y += a4.y; a0.z += a4.z; a0.w += a4.w;
  a1.x += a5.x; a1.y += a5.y; a1.z += a5.z; a1.w += a5.w;
  a2.x += a6.x; a2.y += a6.y; a2.z += a6.z; a2.w += a6.w;
  a3.x += a7.x; a3.y += a7.y; a3.z += a7.z; a3.w += a7.w;
  const float inv = 1.f / (float)len;
  const float m0 = (a0.x + a1.x + a2.x + a3.x) * inv;
  const float m1 = (a0.y + a1.y + a2.y + a3.y) * inv;
  const float m2 = (a0.z + a1.z + a2.z + a3.z) * inv;
  const float m3 = (a0.w + a1.w + a2.w + a3.w) * inv;

  uint2* crow = (uint2*)(combined + (size_t)b * K2);
  crow[lane] = sp;                        // self half: bf16 passthrough
  uint2 pm; pm.x = pack2(m0, m1); pm.y = pack2(m2, m3);
  crow[64 + lane] = pm;
}

// ---------------------------------------------------------------------------
// GEMM: out[M,256] = relu(combined[M,512] @ w1bf[256,512]^T), f32 out.
// Round-0 proven: 128x128 tile, BK=32, 4 waves 2x2, wave 64x64 = 4x4 MFMA
// 16x16x32 bf16, uint4 LDS staging with +8 row pad.
// ---------------------------------------------------------------------------
#define BM 128
#define BN 128
#define LDST 40   // 32 + 8 pad elements

__global__ __launch_bounds__(256) void gemm_kernel(
    const u16* __restrict__ A,   // [M, 512] combined bf16 (K-contiguous)
    const u16* __restrict__ W,   // [256, 512] w1 bf16 (K-contiguous)
    float* __restrict__ C,       // [M, 256] f32
    int M) {
  __shared__ u16 As[BM * LDST];
  __shared__ u16 Bs[BN * LDST];

  const int tid  = threadIdx.x;
  const int wave = tid >> 6;
  const int lane = tid & 63;
  const int m0 = blockIdx.x * BM;
  const int n0 = blockIdx.y * BN;

  const int wr = (wave >> 1) * 64;
  const int wc = (wave & 1) * 64;

  f32x4 acc[4][4] = {};

  const int r16 = lane & 15;
  const int kq  = (lane >> 4) * 8;

  const int srow = tid >> 2;
  const int skc  = tid & 3;

  for (int k0 = 0; k0 < K2; k0 += 32) {
#pragma unroll
    for (int i = 0; i < 2; ++i) {
      const int row = i * 64 + srow;
      int ar = m0 + row; if (ar >= M) ar = M - 1;
      const uint4 va = ((const uint4*)(A + (size_t)ar * K2 + k0))[skc];
      *(uint4*)&As[row * LDST + skc * 8] = va;
      const uint4 vb = ((const uint4*)(W + (size_t)(n0 + row) * K2 + k0))[skc];
      *(uint4*)&Bs[row * LDST + skc * 8] = vb;
    }
    __syncthreads();

    short8 af[4], bf[4];
#pragma unroll
    for (int i = 0; i < 4; ++i)
      af[i] = *(const short8*)&As[(wr + i * 16 + r16) * LDST + kq];
#pragma unroll
    for (int j = 0; j < 4; ++j)
      bf[j] = *(const short8*)&Bs[(wc + j * 16 + r16) * LDST + kq];

#pragma unroll
    for (int i = 0; i < 4; ++i)
#pragma unroll
      for (int j = 0; j < 4; ++j)
        acc[i][j] = __builtin_amdgcn_mfma_f32_16x16x32_bf16(af[i], bf[j],
                                                            acc[i][j], 0, 0, 0);
    __syncthreads();
  }

  // Epilogue: C/D layout col = lane&15, row = (lane>>4)*4 + reg  [m89]
#pragma unroll
  for (int i = 0; i < 4; ++i) {
#pragma unroll
    for (int r = 0; r < 4; ++r) {
      const int row = m0 + wr + i * 16 + (lane >> 4) * 4 + r;
      if (row < M) {
#pragma unroll
        for (int j = 0; j < 4; ++j) {
          const int col = n0 + wc + j * 16 + (lane & 15);
          float v = acc[i][j][r];
          C[(size_t)row * OUTF + col] = v > 0.f ? v : 0.f;
        }
      }
    }
  }
}

// ---------------------------------------------------------------------------
extern "C" void kernel_launch(void* const* d_in, const int* in_sizes, int n_in,
                              void* d_out, int out_size, void* d_ws, size_t ws_size,
                              hipStream_t stream) {
  const float* feats = (const float*)d_in[0];  // [100000, 256] f32
  const int* nodes   = (const int*)d_in[1];    // [20000]
  const int* neighs  = (const int*)d_in[2];    // [20000, 25]
  const int* lens    = (const int*)d_in[3];    // [20000]
  // d_in[4] = w0 — dead: layer-0 output is discarded by the reference loop.
  const float* w1    = (const float*)d_in[5];  // [256, 512] f32
  float* out = (float*)d_out;                  // [20000, 256] f32

  char* ws = (char*)d_ws;
  u16* featsbf  = (u16*)(ws + WS_FB_OFF);      // [100000, 256] bf16
  u16* combined = (u16*)(ws + WS_CMB_OFF);     // [20000, 512] bf16
  u16* w1bf     = (u16*)(ws + WS_W1_OFF);      // [256, 512] bf16

  convw_kernel<<<512, 256, 0, stream>>>(w1, w1bf);
  cast_kernel<<<NNODES * FEAT / 8 / 256, 256, 0, stream>>>(feats, featsbf);
  agg_kernel<<<NB / 4, 256, 0, stream>>>(featsbf, nodes, neighs, lens, combined);

  dim3 grid((NB + BM - 1) / BM, OUTF / BN);    // 157 x 2
  gemm_kernel<<<grid, 256, 0, stream>>>(combined, w1bf, out, NB);
}

// Round 8
// 205.995 us; speedup vs baseline: 1.2264x; 1.0099x over previous
//
#include <hip/hip_runtime.h>

typedef unsigned short u16;
typedef unsigned int   u32;

#define NB     20000   // batch of target nodes
#define SNB    25      // sampled neighbors (padded)
#define FEAT   256
#define K2     512     // 2*FEAT
#define OUTF   256
#define NNODES 100000

// Round-8: cast-then-gather (R7 pipeline) with COALESCED cast.
// Evidence: R7 kernel total = 87us vs 63us ideal; agg (~21us, R6 final_kernel)
// and gemm (~15us, R0 subtraction) are pinned, so the ~25us excess is the
// cast's stride-32 lane addressing (two float4 loads at 2i/2i+1 per thread).
// Fix: thread t loads float4 at [t] (unit lane stride, 1KB/wave), stores
// uint2 at [t] (512B/wave). Everything else byte-identical to R7.
//
// d_ws layout (bytes):
//   [0]           featsbf bf16 [100000][256] = 51,200,000
//   [51,200,000]  combined bf16 [20000][512] = 20,480,000
//   [71,680,000]  w1bf bf16 [256][512]       =    262,144
#define WS_FB_OFF   0
#define WS_CMB_OFF  (NNODES * FEAT * 2)
#define WS_W1_OFF   (WS_CMB_OFF + NB * K2 * 2)

typedef __attribute__((ext_vector_type(8))) short short8;
typedef __attribute__((ext_vector_type(4))) float f32x4;

__device__ __forceinline__ u32 f2bf(float f) {
  union { u32 i; float f; } x; x.f = f;
  return (x.i + 0x7fffu + ((x.i >> 16) & 1u)) >> 16;  // RNE
}
__device__ __forceinline__ u32 pack2(float a, float b) {
  return f2bf(a) | (f2bf(b) << 16);
}
__device__ __forceinline__ float4 unbf4(uint2 u) {
  float4 r;
  r.x = __uint_as_float(u.x << 16);
  r.y = __uint_as_float(u.x & 0xffff0000u);
  r.z = __uint_as_float(u.y << 16);
  r.w = __uint_as_float(u.y & 0xffff0000u);
  return r;
}

// ---------------------------------------------------------------------------
// feats f32 -> bf16, fully coalesced: thread t = one float4 load at elem
// index t (16B/lane, unit stride) + one uint2 store (8B/lane).
// 25.6M elems / 4 = 6.4M threads = 25,000 blocks.
// ---------------------------------------------------------------------------
__global__ __launch_bounds__(256) void cast_kernel(
    const float* __restrict__ in, u16* __restrict__ out) {
  const size_t t = (size_t)blockIdx.x * 256 + threadIdx.x;  // float4 index
  const float4 f = ((const float4*)in)[t];
  uint2 o;
  o.x = pack2(f.x, f.y);
  o.y = pack2(f.z, f.w);
  ((uint2*)out)[t] = o;
}

// ---------------------------------------------------------------------------
// w1 f32 -> bf16 (131072 elements).
// ---------------------------------------------------------------------------
__global__ __launch_bounds__(256) void convw_kernel(
    const float* __restrict__ w_raw, u16* __restrict__ w_bf) {
  const int i = blockIdx.x * 256 + threadIdx.x;
  w_bf[i] = (u16)f2bf(w_raw[i]);
}

// ---------------------------------------------------------------------------
// Aggregation over bf16 rows: combined[b,0:256] = featsbf[nodes[b]] (copy);
// combined[b,256:512] = bf16(mean_f32(featsbf[neighs[b,:len]])).
// Proven wave-per-node structure, 8 gathers in flight; 512B rows
// (lane covers 4 feats via uint2 = 8B). No barriers. [unchanged from R7]
// ---------------------------------------------------------------------------
__global__ __launch_bounds__(256) void agg_kernel(
    const u16* __restrict__ fb, const int* __restrict__ nodes,
    const int* __restrict__ neighs, const int* __restrict__ lens,
    u16* __restrict__ combined) {
  const int b    = blockIdx.x * 4 + (threadIdx.x >> 6);  // node id
  const int lane = threadIdx.x & 63;

  const int self = nodes[b];
  const int len  = lens[b];   // guaranteed >= 1
  int myidx = (lane < SNB) ? neighs[b * SNB + lane] : 0;

  const uint2 sp = *(const uint2*)(fb + (size_t)self * FEAT + lane * 4);

  float4 a0 = {0.f, 0.f, 0.f, 0.f}, a1 = a0, a2 = a0, a3 = a0;
  float4 a4 = a0, a5 = a0, a6 = a0, a7 = a0;
  int s = 0;
  for (; s + 8 <= len; s += 8) {
    const int i0 = __shfl(myidx, s);
    const int i1 = __shfl(myidx, s + 1);
    const int i2 = __shfl(myidx, s + 2);
    const int i3 = __shfl(myidx, s + 3);
    const int i4 = __shfl(myidx, s + 4);
    const int i5 = __shfl(myidx, s + 5);
    const int i6 = __shfl(myidx, s + 6);
    const int i7 = __shfl(myidx, s + 7);
    const uint2 q0 = *(const uint2*)(fb + (size_t)i0 * FEAT + lane * 4);
    const uint2 q1 = *(const uint2*)(fb + (size_t)i1 * FEAT + lane * 4);
    const uint2 q2 = *(const uint2*)(fb + (size_t)i2 * FEAT + lane * 4);
    const uint2 q3 = *(const uint2*)(fb + (size_t)i3 * FEAT + lane * 4);
    const uint2 q4 = *(const uint2*)(fb + (size_t)i4 * FEAT + lane * 4);
    const uint2 q5 = *(const uint2*)(fb + (size_t)i5 * FEAT + lane * 4);
    const uint2 q6 = *(const uint2*)(fb + (size_t)i6 * FEAT + lane * 4);
    const uint2 q7 = *(const uint2*)(fb + (size_t)i7 * FEAT + lane * 4);
    float4 v;
    v = unbf4(q0); a0.x += v.x; a0.y += v.y; a0.z += v.z; a0.w += v.w;
    v = unbf4(q1); a1.x += v.x; a1.y += v.y; a1.z += v.z; a1.w += v.w;
    v = unbf4(q2); a2.x += v.x; a2.y += v.y; a2.z += v.z; a2.w += v.w;
    v = unbf4(q3); a3.x += v.x; a3.y += v.y; a3.z += v.z; a3.w += v.w;
    v = unbf4(q4); a4.x += v.x; a4.y += v.y; a4.z += v.z; a4.w += v.w;
    v = unbf4(q5); a5.x += v.x; a5.y += v.y; a5.z += v.z; a5.w += v.w;
    v = unbf4(q6); a6.x += v.x; a6.y += v.y; a6.z += v.z; a6.w += v.w;
    v = unbf4(q7); a7.x += v.x; a7.y += v.y; a7.z += v.z; a7.w += v.w;
  }
  for (; s + 4 <= len; s += 4) {
    const int i0 = __shfl(myidx, s);
    const int i1 = __shfl(myidx, s + 1);
    const int i2 = __shfl(myidx, s + 2);
    const int i3 = __shfl(myidx, s + 3);
    const uint2 q0 = *(const uint2*)(fb + (size_t)i0 * FEAT + lane * 4);
    const uint2 q1 = *(const uint2*)(fb + (size_t)i1 * FEAT + lane * 4);
    const uint2 q2 = *(const uint2*)(fb + (size_t)i2 * FEAT + lane * 4);
    const uint2 q3 = *(const uint2*)(fb + (size_t)i3 * FEAT + lane * 4);
    float4 v;
    v = unbf4(q0); a0.x += v.x; a0.y += v.y; a0.z += v.z; a0.w += v.w;
    v = unbf4(q1); a1.x += v.x; a1.y += v.y; a1.z += v.z; a1.w += v.w;
    v = unbf4(q2); a2.x += v.x; a2.y += v.y; a2.z += v.z; a2.w += v.w;
    v = unbf4(q3); a3.x += v.x; a3.y += v.y; a3.z += v.z; a3.w += v.w;
  }
  for (; s < len; ++s) {
    const int i0 = __shfl(myidx, s);
    const uint2 q0 = *(const uint2*)(fb + (size_t)i0 * FEAT + lane * 4);
    const float4 v = unbf4(q0);
    a0.x += v.x; a0.y += v.y; a0.z += v.z; a0.w += v.w;
  }
  a0.x += a4.x; a0.y += a4.y; a0.z += a4.z; a0.w += a4.w;
  a1.x += a5.x; a1.y += a5.y; a1.z += a5.z; a1.w += a5.w;
  a2.x += a6.x; a2.y += a6.y; a2.z += a6.z; a2.w += a6.w;
  a3.x += a7.x; a3.y += a7.y; a3.z += a7.z; a3.w += a7.w;
  const float inv = 1.f / (float)len;
  const float m0 = (a0.x + a1.x + a2.x + a3.x) * inv;
  const float m1 = (a0.y + a1.y + a2.y + a3.y) * inv;
  const float m2 = (a0.z + a1.z + a2.z + a3.z) * inv;
  const float m3 = (a0.w + a1.w + a2.w + a3.w) * inv;

  uint2* crow = (uint2*)(combined + (size_t)b * K2);
  crow[lane] = sp;                        // self half: bf16 passthrough
  uint2 pm; pm.x = pack2(m0, m1); pm.y = pack2(m2, m3);
  crow[64 + lane] = pm;
}

// ---------------------------------------------------------------------------
// GEMM: out[M,256] = relu(combined[M,512] @ w1bf[256,512]^T), f32 out.
// Round-0 proven: 128x128 tile, BK=32, 4 waves 2x2, wave 64x64 = 4x4 MFMA
// 16x16x32 bf16, uint4 LDS staging with +8 row pad. [unchanged]
// ---------------------------------------------------------------------------
#define BM 128
#define BN 128
#define LDST 40   // 32 + 8 pad elements

__global__ __launch_bounds__(256) void gemm_kernel(
    const u16* __restrict__ A,   // [M, 512] combined bf16 (K-contiguous)
    const u16* __restrict__ W,   // [256, 512] w1 bf16 (K-contiguous)
    float* __restrict__ C,       // [M, 256] f32
    int M) {
  __shared__ u16 As[BM * LDST];
  __shared__ u16 Bs[BN * LDST];

  const int tid  = threadIdx.x;
  const int wave = tid >> 6;
  const int lane = tid & 63;
  const int m0 = blockIdx.x * BM;
  const int n0 = blockIdx.y * BN;

  const int wr = (wave >> 1) * 64;
  const int wc = (wave & 1) * 64;

  f32x4 acc[4][4] = {};

  const int r16 = lane & 15;
  const int kq  = (lane >> 4) * 8;

  const int srow = tid >> 2;
  const int skc  = tid & 3;

  for (int k0 = 0; k0 < K2; k0 += 32) {
#pragma unroll
    for (int i = 0; i < 2; ++i) {
      const int row = i * 64 + srow;
      int ar = m0 + row; if (ar >= M) ar = M - 1;
      const uint4 va = ((const uint4*)(A + (size_t)ar * K2 + k0))[skc];
      *(uint4*)&As[row * LDST + skc * 8] = va;
      const uint4 vb = ((const uint4*)(W + (size_t)(n0 + row) * K2 + k0))[skc];
      *(uint4*)&Bs[row * LDST + skc * 8] = vb;
    }
    __syncthreads();

    short8 af[4], bf[4];
#pragma unroll
    for (int i = 0; i < 4; ++i)
      af[i] = *(const short8*)&As[(wr + i * 16 + r16) * LDST + kq];
#pragma unroll
    for (int j = 0; j < 4; ++j)
      bf[j] = *(const short8*)&Bs[(wc + j * 16 + r16) * LDST + kq];

#pragma unroll
    for (int i = 0; i < 4; ++i)
#pragma unroll
      for (int j = 0; j < 4; ++j)
        acc[i][j] = __builtin_amdgcn_mfma_f32_16x16x32_bf16(af[i], bf[j],
                                                            acc[i][j], 0, 0, 0);
    __syncthreads();
  }

  // Epilogue: C/D layout col = lane&15, row = (lane>>4)*4 + reg  [m89]
#pragma unroll
  for (int i = 0; i < 4; ++i) {
#pragma unroll
    for (int r = 0; r < 4; ++r) {
      const int row = m0 + wr + i * 16 + (lane >> 4) * 4 + r;
      if (row < M) {
#pragma unroll
        for (int j = 0; j < 4; ++j) {
          const int col = n0 + wc + j * 16 + (lane & 15);
          float v = acc[i][j][r];
          C[(size_t)row * OUTF + col] = v > 0.f ? v : 0.f;
        }
      }
    }
  }
}

// ---------------------------------------------------------------------------
extern "C" void kernel_launch(void* const* d_in, const int* in_sizes, int n_in,
                              void* d_out, int out_size, void* d_ws, size_t ws_size,
                              hipStream_t stream) {
  const float* feats = (const float*)d_in[0];  // [100000, 256] f32
  const int* nodes   = (const int*)d_in[1];    // [20000]
  const int* neighs  = (const int*)d_in[2];    // [20000, 25]
  const int* lens    = (const int*)d_in[3];    // [20000]
  // d_in[4] = w0 — dead: layer-0 output is discarded by the reference loop.
  const float* w1    = (const float*)d_in[5];  // [256, 512] f32
  float* out = (float*)d_out;                  // [20000, 256] f32

  char* ws = (char*)d_ws;
  u16* featsbf  = (u16*)(ws + WS_FB_OFF);      // [100000, 256] bf16
  u16* combined = (u16*)(ws + WS_CMB_OFF);     // [20000, 512] bf16
  u16* w1bf     = (u16*)(ws + WS_W1_OFF);      // [256, 512] bf16

  cast_kernel<<<NNODES * FEAT / 4 / 256, 256, 0, stream>>>(feats, featsbf);
  convw_kernel<<<512, 256, 0, stream>>>(w1, w1bf);
  agg_kernel<<<NB / 4, 256, 0, stream>>>(featsbf, nodes, neighs, lens, combined);

  dim3 grid((NB + BM - 1) / BM, OUTF / BN);    // 157 x 2
  gemm_kernel<<<grid, 256, 0, stream>>>(combined, w1bf, out, NB);
}